// Round 20
// baseline (109.207 us; speedup 1.0000x reference)
//
#include <hip/hip_runtime.h>

typedef unsigned short u16;
typedef unsigned int u32;
typedef __bf16 bf16x8 __attribute__((ext_vector_type(8)));
typedef float f32x4 __attribute__((ext_vector_type(4)));
typedef u16 u16x4 __attribute__((ext_vector_type(4)));
typedef u32 u32x2 __attribute__((ext_vector_type(2)));

#define S_LEN 2048
#define NH 16
#define DH 64
#define DM 1024

#define GLDS(gp, lp) __builtin_amdgcn_global_load_lds( \
    (const __attribute__((address_space(1))) void*)(gp), \
    (__attribute__((address_space(3))) void*)(lp), 16, 0, 0)

__device__ __forceinline__ u16 f2bf(float f) {
  unsigned u = __float_as_uint(f);
  u += 0x7FFFu + ((u >> 16) & 1u);
  return (u16)(u >> 16);
}
__device__ __forceinline__ float bf2f(u16 h) {
  return __uint_as_float(((unsigned)h) << 16);
}

// ---------------- convert f32 -> bf16 (x, Wqkv, Wo in one launch) ----------------
__global__ __launch_bounds__(256) void conv3_kernel(const float* __restrict__ a,
                                                    const float* __restrict__ wb,
                                                    const float* __restrict__ wc,
                                                    u16* __restrict__ oa,
                                                    u16* __restrict__ ob,
                                                    u16* __restrict__ oc) {
  int bid = blockIdx.x;
  const float* in;
  u16* out;
  int idx;
  if (bid < 2048)      { in = a;  out = oa; idx = bid; }
  else if (bid < 3584) { in = wb; out = ob; idx = bid - 2048; }
  else                 { in = wc; out = oc; idx = bid - 3584; }
  int i = idx * 2048 + threadIdx.x * 8;
  float4 v0 = *(const float4*)(in + i);
  float4 v1 = *(const float4*)(in + i + 4);
  u16x4 o0, o1;
  o0.x = f2bf(v0.x); o0.y = f2bf(v0.y); o0.z = f2bf(v0.z); o0.w = f2bf(v0.w);
  o1.x = f2bf(v1.x); o1.y = f2bf(v1.y); o1.z = f2bf(v1.z); o1.w = f2bf(v1.w);
  *(u16x4*)(out + i) = o0;
  *(u16x4*)(out + i + 4) = o1;
}

// ---------------- bf16 GEMM: C[M][N] = A[M][K] * B[N][K]^T ----------------
// 128x128 tile, BK=32, 4 waves. 3-deep buffered global_load_lds pipeline with
// COUNTED vmcnt(4) (loads span barriers; one s_barrier per K-step).
// Bank-conflict-free reads via pre-swizzled source + swizzled read slot (r16).
// MODE 0: bf16 C   MODE 1: f32 C   MODE 2: fused RoPE/relayout epilogue.
template <int MODE>
__global__ __launch_bounds__(256) void gemm_bt(const u16* __restrict__ A,
                                               const u16* __restrict__ B,
                                               void* __restrict__ C,
                                               int N, int K,
                                               const float* __restrict__ pi_gate_logit,
                                               u16* __restrict__ qrot,
                                               u16* __restrict__ krot,
                                               u16* __restrict__ vtp) {
  __shared__ __align__(16) u16 smem[24576];  // 3 bufs x (A 4096 + B 4096) u16
  int tid = threadIdx.x;
  int w = tid >> 6, l = tid & 63, lg = l >> 4, lr = l & 15;

  // bijective XCD swizzle (nwg % 8 == 0 for both launches)
  int nwg = gridDim.x * gridDim.y;
  int lid = blockIdx.y * gridDim.x + blockIdx.x;
  int swz = (lid & 7) * (nwg >> 3) + (lid >> 3);
  int bx = swz % gridDim.x, by = swz / gridDim.x;
  int m0 = by * 128, n0 = bx * 128;

  int wm = (w >> 1) * 64, wn = (w & 1) * 64;
  int NK = K >> 5;

  // staging: lane l covers local row l>>2, swizzled source slot
  int srow0 = w * 16 + (l >> 2);
  int srow1 = srow0 + 64;
  int scol = (((l & 3) ^ ((l >> 3) & 3)) * 8);  // pre-swizzled K-offset
  const u16* gA0 = A + (size_t)(m0 + srow0) * K + scol;
  const u16* gA1 = A + (size_t)(m0 + srow1) * K + scol;
  const u16* gB0 = B + (size_t)(n0 + srow0) * K + scol;
  const u16* gB1 = B + (size_t)(n0 + srow1) * K + scol;

  auto stage = [&](int bufi) {
    u16* ab = smem + bufi * 8192;
    u16* bb = ab + 4096;
    GLDS(gA0, ab + w * 512);
    GLDS(gA1, ab + (4 + w) * 512);
    GLDS(gB0, bb + w * 512);
    GLDS(gB1, bb + (4 + w) * 512);
    gA0 += 32; gA1 += 32; gB0 += 32; gB1 += 32;
  };

  // read slot: sx = lg ^ ((lr>>1)&3)  (per-thread constant)
  int sx = lg ^ ((lr >> 1) & 3);

  f32x4 zero4 = {0.f, 0.f, 0.f, 0.f};
  f32x4 acc[4][4];
#pragma unroll
  for (int mt = 0; mt < 4; ++mt)
#pragma unroll
    for (int nt = 0; nt < 4; ++nt) acc[mt][nt] = zero4;

  stage(0);
  stage(1);

  int p = 0;   // buffer being computed this iteration
  int pn = 2;  // next buffer to stage
  for (int kt = 0; kt < NK; ++kt) {
    // wait only the OLDEST buffer's 4 loads; newer 4 stay in flight
    if (kt + 1 < NK) asm volatile("s_waitcnt vmcnt(4)" ::: "memory");
    else             asm volatile("s_waitcnt vmcnt(0)" ::: "memory");
    __builtin_amdgcn_s_barrier();       // all waves staged buf p; compute(kt-1) done
    __builtin_amdgcn_sched_barrier(0);  // pin: no hoisting across the barrier
    if (kt + 2 < NK) {
      stage(pn);
      pn = (pn == 2) ? 0 : pn + 1;
    }

    const u16* ab = smem + p * 8192;
    const u16* bb = ab + 4096;
    bf16x8 af[4], bfr[4];
#pragma unroll
    for (int mt = 0; mt < 4; ++mt)
      af[mt] = *(const bf16x8*)(ab + (wm + mt * 16 + lr) * 32 + sx * 8);
#pragma unroll
    for (int nt = 0; nt < 4; ++nt)
      bfr[nt] = *(const bf16x8*)(bb + (wn + nt * 16 + lr) * 32 + sx * 8);
    __builtin_amdgcn_s_setprio(1);
#pragma unroll
    for (int mt = 0; mt < 4; ++mt)
#pragma unroll
      for (int nt = 0; nt < 4; ++nt)
        acc[mt][nt] = __builtin_amdgcn_mfma_f32_16x16x32_bf16(af[mt], bfr[nt], acc[mt][nt], 0, 0, 0);
    __builtin_amdgcn_s_setprio(0);

    p = (p == 2) ? 0 : p + 1;
  }

  if constexpr (MODE != 2) {
#pragma unroll
    for (int mt = 0; mt < 4; ++mt)
#pragma unroll
      for (int nt = 0; nt < 4; ++nt)
#pragma unroll
        for (int r = 0; r < 4; ++r) {
          int row = m0 + wm + mt * 16 + lg * 4 + r;
          int col = n0 + wn + nt * 16 + lr;
          float v = acc[mt][nt][r];
          if (MODE == 1) ((float*)C)[(size_t)row * N + col] = v;
          else           ((u16*)C)[(size_t)row * N + col] = f2bf(v);
        }
  } else {
    // ---- fused RoPE epilogue ----
    int region = n0 >> 10;
    int hh = ((n0 + wn) >> 6) & 15;
    if (region < 2) {
      float pg = 1.0f / (1.0f + __expf(-pi_gate_logit[hh]));
      float sc = region ? 1.0f : 0.18033688011111772f;  // Q: 0.125*log2(e)
      u16* dst = region ? krot : qrot;
      float cfreq[4];
#pragma unroll
      for (int nt = 0; nt < 4; ++nt) {
        float pp = (float)((nt * 16 + lr) >> 1);
        cfreq[nt] = exp2f((1.0f - pp * 0.03125f) * 1.6514961294723187f) * pg;
      }
#pragma unroll
      for (int mt = 0; mt < 4; ++mt)
#pragma unroll
        for (int r = 0; r < 4; ++r) {
          int row = m0 + wm + mt * 16 + lg * 4 + r;
          int s = row & 2047, bb2 = row >> 11;
          size_t base = ((size_t)((bb2 * 16 + hh) * 2048 + s)) * 64;
          float fs = (float)s;
#pragma unroll
          for (int nt = 0; nt < 4; ++nt) {
            float mine = acc[mt][nt][r];
            float other = __shfl_xor(mine, 1);
            float rev = fs * cfreq[nt] * 0.15915494309189535f;
            rev -= floorf(rev);
            float cs = __builtin_amdgcn_cosf(rev);
            float sn = __builtin_amdgcn_sinf(rev);
            float rot = (lr & 1) ? (other * sn + mine * cs)
                                 : (mine * cs - other * sn);
            dst[base + nt * 16 + lr] = f2bf(rot * sc);
          }
        }
    } else {
      // V: transposed store vt[bh][d][s], 4 consecutive s per 8B store
#pragma unroll
      for (int mt = 0; mt < 4; ++mt)
#pragma unroll
        for (int nt = 0; nt < 4; ++nt) {
          int row0r = m0 + wm + mt * 16 + lg * 4;
          int s = row0r & 2047, bb2 = row0r >> 11;
          int d = nt * 16 + lr;
          u16x4 o;
          o.x = f2bf(acc[mt][nt][0]); o.y = f2bf(acc[mt][nt][1]);
          o.z = f2bf(acc[mt][nt][2]); o.w = f2bf(acc[mt][nt][3]);
          *(u16x4*)(vtp + ((size_t)((bb2 * 16 + hh) * 64 + d)) * 2048 + s) = o;
        }
    }
  }
}

// ---------------- flash attention tile compute (static indexing) ----------------
// Swapped QK^T: sacc[nt][r] = S^T[kv=nt*16+lg*4+r][q=w*16+lr].
// exp2-domain; decay bias + (tb - mrun) folded into MFMA C-init.
template <bool DIAG>
__device__ __forceinline__ void attn_tile(const unsigned char* __restrict__ kbuf,
                                          const unsigned char* __restrict__ vbuf,
                                          float mt, const float (&cbv)[16],
                                          const bf16x8 (&qf)[2],
                                          f32x4 (&oacc)[4],
                                          float& mrun, float& lrun,
                                          int lg, int lr, int il,
                                          unsigned char* pbuf) {
  // ---- QK^T with C-init = column bias + (tb - mrun) ----
  f32x4 sacc[4];
#pragma unroll
  for (int nt = 0; nt < 4; ++nt)
#pragma unroll
    for (int r = 0; r < 4; ++r) sacc[nt][r] = cbv[nt * 4 + r] + mt;
  __builtin_amdgcn_s_setprio(1);
#pragma unroll
  for (int nt = 0; nt < 4; ++nt)
#pragma unroll
    for (int kk = 0; kk < 2; ++kk) {
      int row = nt * 16 + lr;
      int sl_ = lg + kk * 4;
      bf16x8 kf = *(const bf16x8*)(kbuf + row * 128 + ((sl_ ^ (row & 7)) << 4));
      sacc[nt] = __builtin_amdgcn_mfma_f32_16x16x32_bf16(kf, qf[kk], sacc[nt], 0, 0, 0);
    }
  __builtin_amdgcn_s_setprio(0);

  // ---- (diagonal) causal mask ----
  float pv[16];
#pragma unroll
  for (int nt = 0; nt < 4; ++nt)
#pragma unroll
    for (int r = 0; r < 4; ++r) {
      float v = sacc[nt][r];
      if (DIAG) {
        int jl = nt * 16 + lg * 4 + r;
        v = (jl <= il) ? v : -1e30f;
      }
      pv[nt * 4 + r] = v;
    }

  // ---- row max (relative to mrun): in-lane tree + 2 shuffles ----
  float m1 = pv[0];
#pragma unroll
  for (int i = 1; i < 16; ++i) m1 = fmaxf(m1, pv[i]);
  m1 = fmaxf(m1, __shfl_xor(m1, 16));
  m1 = fmaxf(m1, __shfl_xor(m1, 32));

  // ---- defer-max rescale (THR=8 in log2 units) ----
  if (__ballot(m1 > 8.f)) {
    float d = fmaxf(m1, 0.f);
    float fac = __builtin_amdgcn_exp2f(-d);
    mrun += d;
    lrun *= fac;
    int fi = __float_as_int(fac);
    float facr[4];
#pragma unroll
    for (int r = 0; r < 4; ++r)
      facr[r] = __int_as_float(__builtin_amdgcn_ds_bpermute((4 * lg + r) << 2, fi));
#pragma unroll
    for (int nt = 0; nt < 4; ++nt)
#pragma unroll
      for (int r = 0; r < 4; ++r) oacc[nt][r] *= facr[r];
#pragma unroll
    for (int i = 0; i < 16; ++i) pv[i] -= d;
  }

  // ---- exp2 + row sum ----
  float p[16];
  float rsum = 0.f;
#pragma unroll
  for (int i = 0; i < 16; ++i) {
    p[i] = __builtin_amdgcn_exp2f(pv[i]);
    rsum += p[i];
  }
  rsum += __shfl_xor(rsum, 16);
  rsum += __shfl_xor(rsum, 32);
  lrun += rsum;

  // ---- pack P -> per-wave swizzled LDS (4x ds_write_b64) ----
#pragma unroll
  for (int nt = 0; nt < 4; ++nt) {
    u32x2 pk2;
    asm("v_cvt_pk_bf16_f32 %0, %1, %2" : "=v"(pk2.x)
        : "v"(p[nt * 4 + 0]), "v"(p[nt * 4 + 1]));
    asm("v_cvt_pk_bf16_f32 %0, %1, %2" : "=v"(pk2.y)
        : "v"(p[nt * 4 + 2]), "v"(p[nt * 4 + 3]));
    // base has bits 0-3 free of the XOR (swz bits are 4-6) -> +0/+4 contiguous
    *(u32x2*)(pbuf + ((lr * 128 + nt * 32 + lg * 8) ^ ((lr & 7) << 4))) = pk2;
  }
  asm volatile("s_waitcnt lgkmcnt(0)" ::: "memory");

  bf16x8 pf[2];
#pragma unroll
  for (int kk = 0; kk < 2; ++kk)
    pf[kk] = *(const bf16x8*)(pbuf + ((lr * 128 + (lg + 4 * kk) * 16) ^ ((lr & 7) << 4)));

  // ---- PV from LDS ----
  __builtin_amdgcn_s_setprio(1);
#pragma unroll
  for (int nt = 0; nt < 4; ++nt)
#pragma unroll
    for (int kk = 0; kk < 2; ++kk) {
      int row = nt * 16 + lr;
      int sl_ = lg + kk * 4;
      bf16x8 vf = *(const bf16x8*)(vbuf + row * 128 + ((sl_ ^ (row & 7)) << 4));
      oacc[nt] = __builtin_amdgcn_mfma_f32_16x16x32_bf16(pf[kk], vf, oacc[nt], 0, 0, 0);
    }
  __builtin_amdgcn_s_setprio(0);
}

// Flash attention: double-buffered LDS K/V, ONE barrier per tile, prefetch
// issued AFTER the barrier so it overlaps compute. Heavy-first grid.
// __launch_bounds__(256,4): 4 blocks/CU x 40KB LDS = 160KB exactly -> whole
// 1024-block grid co-resident (4/CU), 16 waves/CU for latency hiding.
__global__ __launch_bounds__(256, 4) void attn_kernel(const u16* __restrict__ qrot,
                                                      const u16* __restrict__ krot,
                                                      const u16* __restrict__ vt,
                                                      const float* __restrict__ log_xi,
                                                      const float* __restrict__ e_gate_logit,
                                                      u16* __restrict__ attnout) {
  int bh = blockIdx.x;
  int qt = 31 - blockIdx.y;
  int b = bh >> 4, h = bh & 15;
  int tid = threadIdx.x, w = tid >> 6, l = tid & 63, lg = l >> 4, lr = l & 15;
  int q0 = qt * 64;
  int il = w * 16 + lr;  // this lane's q-row, local to the 64-row tile

  const float L2E = 1.4426950408889634f;
  float eg = 1.0f / (1.0f + __expf(-e_gate_logit[h]));
  float cdec2 = eg * __expf(-log_xi[h]) * L2E;  // (e_g/xi) * log2e

  __shared__ __align__(16) unsigned char smem[40960];
  // [0:16384) kbuf[2], [16384:32768) vbuf[2], [32768:40960) pbuf per-wave
  unsigned char* pbuf = smem + 32768 + (w << 11);

  const size_t bhS = (size_t)bh * S_LEN;
  const u16* kb0 = krot + bhS * DH;
  const u16* vb0 = vt + (size_t)bh * DH * S_LEN;

  bf16x8 qf[2];
  {
    const u16* qp = qrot + (bhS + q0 + il) * DH + lg * 8;
    qf[0] = *(const bf16x8*)(qp);
    qf[1] = *(const bf16x8*)(qp + 32);
  }

  float cbv[16];
#pragma unroll
  for (int nt = 0; nt < 4; ++nt)
#pragma unroll
    for (int r = 0; r < 4; ++r)
      cbv[nt * 4 + r] = (float)(nt * 16 + lg * 4 + r) * cdec2;

  // staging geometry: 512 chunks of 16B per 8KB tile; this thread's 2 chunks
  int c0 = tid, c1 = 256 + tid;
  int row0 = c0 >> 3, sl0 = c0 & 7;
  int row1 = c1 >> 3, sl1 = c1 & 7;

  bf16x8 kr[2], vr[2];
  auto load_kv = [&](int t) {
    kr[0] = *(const bf16x8*)(kb0 + (size_t)(t * 64 + row0) * DH + sl0 * 8);
    kr[1] = *(const bf16x8*)(kb0 + (size_t)(t * 64 + row1) * DH + sl1 * 8);
    vr[0] = *(const bf16x8*)(vb0 + (size_t)row0 * S_LEN + t * 64 + sl0 * 8);
    vr[1] = *(const bf16x8*)(vb0 + (size_t)row1 * S_LEN + t * 64 + sl1 * 8);
  };
  auto stage = [&](int p) {
    unsigned char* kb = smem + p * 8192;
    unsigned char* vb = smem + 16384 + p * 8192;
    *(bf16x8*)(kb + row0 * 128 + ((sl0 ^ (row0 & 7)) << 4)) = kr[0];
    *(bf16x8*)(kb + row1 * 128 + ((sl1 ^ (row1 & 7)) << 4)) = kr[1];
    *(bf16x8*)(vb + row0 * 128 + ((sl0 ^ (row0 & 7)) << 4)) = vr[0];
    *(bf16x8*)(vb + row1 * 128 + ((sl1 ^ (row1 & 7)) << 4)) = vr[1];
  };

  f32x4 zero4 = {0.f, 0.f, 0.f, 0.f};
  f32x4 oacc[4];
#pragma unroll
  for (int nt = 0; nt < 4; ++nt) oacc[nt] = zero4;
  float mrun = 0.f, lrun = 0.f;

  load_kv(0);
  float step = 64.f * cdec2;
  float tb = 0.f;
  int p = 0;
  for (int t = 0; t < qt; ++t, tb += step, p ^= 1) {
    stage(p);           // dataflow-waits this tile's loads (issued last iter)
    __syncthreads();    // buf p visible; nothing outstanding -> free drain
    load_kv(t + 1);     // prefetch AFTER barrier: overlaps tile(p) compute
    attn_tile<false>(smem + p * 8192, smem + 16384 + p * 8192, tb - mrun, cbv,
                     qf, oacc, mrun, lrun, lg, lr, il, pbuf);
  }
  stage(p);
  __syncthreads();
  attn_tile<true>(smem + p * 8192, smem + 16384 + p * 8192, tb - mrun, cbv,
                  qf, oacc, mrun, lrun, lg, lr, il, pbuf);

  // ---- epilogue: redistribute l (lane p in 0..15 holds q-row p's sum) ----
  float lfin[4];
  int li = __float_as_int(lrun);
#pragma unroll
  for (int r = 0; r < 4; ++r)
    lfin[r] = __int_as_float(__builtin_amdgcn_ds_bpermute((4 * lg + r) << 2, li));
#pragma unroll
  for (int nt = 0; nt < 4; ++nt)
#pragma unroll
    for (int r = 0; r < 4; ++r) {
      int srow = q0 + w * 16 + lg * 4 + r;
      int col = h * DH + nt * 16 + lr;
      attnout[((size_t)b * S_LEN + srow) * DM + col] = f2bf(oacc[nt][r] / lfin[r]);
    }
}

// ---------------- launch ----------------
extern "C" void kernel_launch(void* const* d_in, const int* in_sizes, int n_in,
                              void* d_out, int out_size, void* d_ws, size_t ws_size,
                              hipStream_t stream) {
  const float* x    = (const float*)d_in[0];
  const float* Wqkv = (const float*)d_in[1];
  const float* Wo   = (const float*)d_in[2];
  const float* log_xi        = (const float*)d_in[3];
  const float* pi_gate_logit = (const float*)d_in[4];
  const float* e_gate_logit  = (const float*)d_in[5];

  u16* xb     = (u16*)d_ws;                 // 4096x1024
  u16* wqkvb  = xb + 4194304;               // 3072x1024
  u16* wob    = wqkvb + 3145728;            // 1024x1024
  u16* qrot   = wob + 1048576;              // 32x2048x64
  u16* krot   = qrot + 4194304;
  u16* vt     = krot + 4194304;             // 32x64x2048
  u16* attno  = vt + 4194304;               // 4096x1024

  conv3_kernel<<<4096, 256, 0, stream>>>(x, Wqkv, Wo, xb, wqkvb, wob);

  // GEMM1 with fused RoPE/relayout epilogue (writes qrot/krot/vt directly)
  gemm_bt<2><<<dim3(24, 32), 256, 0, stream>>>(xb, wqkvb, nullptr, 3072, 1024,
                                               pi_gate_logit, qrot, krot, vt);

  attn_kernel<<<dim3(32, 32), 256, 0, stream>>>(qrot, krot, vt, log_xi, e_gate_logit, attno);

  gemm_bt<1><<<dim3(8, 32), 256, 0, stream>>>(attno, wob, d_out, 1024, 1024,
                                              nullptr, nullptr, nullptr, nullptr);
}

// Round 21
// 101.489 us; speedup vs baseline: 1.0760x; 1.0760x over previous
//
#include <hip/hip_runtime.h>

typedef unsigned short u16;
typedef unsigned int u32;
typedef __bf16 bf16x8 __attribute__((ext_vector_type(8)));
typedef float f32x4 __attribute__((ext_vector_type(4)));
typedef u16 u16x4 __attribute__((ext_vector_type(4)));

#define S_LEN 2048
#define NH 16
#define DH 64
#define DM 1024

#define GLDS(gp, lp) __builtin_amdgcn_global_load_lds( \
    (const __attribute__((address_space(1))) void*)(gp), \
    (__attribute__((address_space(3))) void*)(lp), 16, 0, 0)

__device__ __forceinline__ u16 f2bf(float f) {
  unsigned u = __float_as_uint(f);
  u += 0x7FFFu + ((u >> 16) & 1u);
  return (u16)(u >> 16);
}
__device__ __forceinline__ float bf2f(u16 h) {
  return __uint_as_float(((unsigned)h) << 16);
}

// ---------------- convert f32 -> bf16 (x, Wqkv, Wo in one launch) ----------------
__global__ __launch_bounds__(256) void conv3_kernel(const float* __restrict__ a,
                                                    const float* __restrict__ wb,
                                                    const float* __restrict__ wc,
                                                    u16* __restrict__ oa,
                                                    u16* __restrict__ ob,
                                                    u16* __restrict__ oc) {
  int bid = blockIdx.x;
  const float* in;
  u16* out;
  int idx;
  if (bid < 2048)      { in = a;  out = oa; idx = bid; }
  else if (bid < 3584) { in = wb; out = ob; idx = bid - 2048; }
  else                 { in = wc; out = oc; idx = bid - 3584; }
  int i = idx * 2048 + threadIdx.x * 8;
  float4 v0 = *(const float4*)(in + i);
  float4 v1 = *(const float4*)(in + i + 4);
  u16x4 o0, o1;
  o0.x = f2bf(v0.x); o0.y = f2bf(v0.y); o0.z = f2bf(v0.z); o0.w = f2bf(v0.w);
  o1.x = f2bf(v1.x); o1.y = f2bf(v1.y); o1.z = f2bf(v1.z); o1.w = f2bf(v1.w);
  *(u16x4*)(out + i) = o0;
  *(u16x4*)(out + i + 4) = o1;
}

// ---------------- bf16 GEMM: C[M][N] = A[M][K] * B[N][K]^T ----------------
// 128x128 tile, BK=32, 4 waves. 3-deep buffered global_load_lds pipeline with
// COUNTED vmcnt (loads span barriers; only one s_barrier per K-step).
// MODE 0: bf16 C   MODE 1: f32 C   MODE 2: fused RoPE/relayout epilogue.
template <int MODE>
__global__ __launch_bounds__(256) void gemm_bt(const u16* __restrict__ A,
                                               const u16* __restrict__ B,
                                               void* __restrict__ C,
                                               int N, int K,
                                               const float* __restrict__ pi_gate_logit,
                                               u16* __restrict__ qrot,
                                               u16* __restrict__ krot,
                                               u16* __restrict__ vtp) {
  __shared__ __align__(16) u16 smem[24576];  // 3 bufs x (A 4096 + B 4096)
  int tid = threadIdx.x;
  int w = tid >> 6, l = tid & 63, lg = l >> 4, lr = l & 15;

  // bijective XCD swizzle (nwg % 8 == 0 for both launches)
  int nwg = gridDim.x * gridDim.y;
  int lid = blockIdx.y * gridDim.x + blockIdx.x;
  int swz = (lid & 7) * (nwg >> 3) + (lid >> 3);
  int bx = swz % gridDim.x, by = swz / gridDim.x;
  int m0 = by * 128, n0 = bx * 128;

  int wm = (w >> 1) * 64, wn = (w & 1) * 64;
  int NK = K >> 5;

  int srow0 = w * 16 + (l >> 2);
  int srow1 = srow0 + 64;
  int scol = (l & 3) * 8;
  const u16* gA0 = A + (size_t)(m0 + srow0) * K + scol;
  const u16* gA1 = A + (size_t)(m0 + srow1) * K + scol;
  const u16* gB0 = B + (size_t)(n0 + srow0) * K + scol;
  const u16* gB1 = B + (size_t)(n0 + srow1) * K + scol;

  auto stage = [&](int bufi) {
    u16* ab = smem + bufi * 8192;
    u16* bb = ab + 4096;
    GLDS(gA0, ab + w * 512);
    GLDS(gA1, ab + (4 + w) * 512);
    GLDS(gB0, bb + w * 512);
    GLDS(gB1, bb + (4 + w) * 512);
    gA0 += 32; gA1 += 32; gB0 += 32; gB1 += 32;
  };

  f32x4 zero4 = {0.f, 0.f, 0.f, 0.f};
  f32x4 acc[4][4];
#pragma unroll
  for (int mt = 0; mt < 4; ++mt)
#pragma unroll
    for (int nt = 0; nt < 4; ++nt) acc[mt][nt] = zero4;

  stage(0);
  stage(1);

  int p = 0;   // buffer being computed this iteration
  int pn = 2;  // next buffer to stage
  for (int kt = 0; kt < NK; ++kt) {
    // wait only the OLDEST buffer's 4 loads; newer 4 stay in flight
    if (kt + 1 < NK) asm volatile("s_waitcnt vmcnt(4)" ::: "memory");
    else             asm volatile("s_waitcnt vmcnt(0)" ::: "memory");
    __builtin_amdgcn_s_barrier();       // all waves staged buf p; compute(kt-1) done
    __builtin_amdgcn_sched_barrier(0);  // pin: no hoisting across the barrier
    if (kt + 2 < NK) {
      stage(pn);
      pn = (pn == 2) ? 0 : pn + 1;
    }

    const u16* ab = smem + p * 8192;
    const u16* bb = ab + 4096;
    bf16x8 af[4], bfr[4];
#pragma unroll
    for (int mt = 0; mt < 4; ++mt)
      af[mt] = *(const bf16x8*)(ab + (wm + mt * 16 + lr) * 32 + lg * 8);
#pragma unroll
    for (int nt = 0; nt < 4; ++nt)
      bfr[nt] = *(const bf16x8*)(bb + (wn + nt * 16 + lr) * 32 + lg * 8);
    __builtin_amdgcn_s_setprio(1);
#pragma unroll
    for (int mt = 0; mt < 4; ++mt)
#pragma unroll
      for (int nt = 0; nt < 4; ++nt)
        acc[mt][nt] = __builtin_amdgcn_mfma_f32_16x16x32_bf16(af[mt], bfr[nt], acc[mt][nt], 0, 0, 0);
    __builtin_amdgcn_s_setprio(0);

    p = (p == 2) ? 0 : p + 1;
  }

  if constexpr (MODE != 2) {
#pragma unroll
    for (int mt = 0; mt < 4; ++mt)
#pragma unroll
      for (int nt = 0; nt < 4; ++nt)
#pragma unroll
        for (int r = 0; r < 4; ++r) {
          int row = m0 + wm + mt * 16 + lg * 4 + r;
          int col = n0 + wn + nt * 16 + lr;
          float v = acc[mt][nt][r];
          if (MODE == 1) ((float*)C)[(size_t)row * N + col] = v;
          else           ((u16*)C)[(size_t)row * N + col] = f2bf(v);
        }
  } else {
    // ---- fused RoPE epilogue ----
    int region = n0 >> 10;
    int hh = ((n0 + wn) >> 6) & 15;
    if (region < 2) {
      float pg = 1.0f / (1.0f + __expf(-pi_gate_logit[hh]));
      float sc = region ? 1.0f : 0.18033688011111772f;  // Q: 0.125*log2(e)
      u16* dst = region ? krot : qrot;
      float cfreq[4];
#pragma unroll
      for (int nt = 0; nt < 4; ++nt) {
        float pp = (float)((nt * 16 + lr) >> 1);
        cfreq[nt] = exp2f((1.0f - pp * 0.03125f) * 1.6514961294723187f) * pg;
      }
#pragma unroll
      for (int mt = 0; mt < 4; ++mt)
#pragma unroll
        for (int r = 0; r < 4; ++r) {
          int row = m0 + wm + mt * 16 + lg * 4 + r;
          int s = row & 2047, bb2 = row >> 11;
          size_t base = ((size_t)((bb2 * 16 + hh) * 2048 + s)) * 64;
          float fs = (float)s;
#pragma unroll
          for (int nt = 0; nt < 4; ++nt) {
            float mine = acc[mt][nt][r];
            float other = __shfl_xor(mine, 1);
            float rev = fs * cfreq[nt] * 0.15915494309189535f;
            rev -= floorf(rev);
            float cs = __builtin_amdgcn_cosf(rev);
            float sn = __builtin_amdgcn_sinf(rev);
            float rot = (lr & 1) ? (other * sn + mine * cs)
                                 : (mine * cs - other * sn);
            dst[base + nt * 16 + lr] = f2bf(rot * sc);
          }
        }
    } else {
      // V: transposed store vt[bh][d][s], 4 consecutive s per 8B store
#pragma unroll
      for (int mt = 0; mt < 4; ++mt)
#pragma unroll
        for (int nt = 0; nt < 4; ++nt) {
          int row0r = m0 + wm + mt * 16 + lg * 4;
          int s = row0r & 2047, bb2 = row0r >> 11;
          int d = nt * 16 + lr;
          u16x4 o;
          o.x = f2bf(acc[mt][nt][0]); o.y = f2bf(acc[mt][nt][1]);
          o.z = f2bf(acc[mt][nt][2]); o.w = f2bf(acc[mt][nt][3]);
          *(u16x4*)(vtp + ((size_t)((bb2 * 16 + hh) * 64 + d)) * 2048 + s) = o;
        }
    }
  }
}

// ---------------- flash attention tile compute (static indexing) ----------------
// Swapped QK^T: sacc[nt][r] = S^T[kv=nt*16+lg*4+r][q=w*16+lr].
// exp2-domain; decay bias + (tb - mrun) folded into MFMA C-init.
template <bool DIAG>
__device__ __forceinline__ void attn_tile(const unsigned char* __restrict__ kbuf,
                                          const unsigned char* __restrict__ vbuf,
                                          float mt, const float (&cbv)[16],
                                          const bf16x8 (&qf)[2],
                                          f32x4 (&oacc)[4],
                                          float& mrun, float& lrun,
                                          int lg, int lr, int il,
                                          unsigned char* pbuf) {
  // ---- QK^T with C-init = column bias + (tb - mrun) ----
  f32x4 sacc[4];
#pragma unroll
  for (int nt = 0; nt < 4; ++nt)
#pragma unroll
    for (int r = 0; r < 4; ++r) sacc[nt][r] = cbv[nt * 4 + r] + mt;
  __builtin_amdgcn_s_setprio(1);
#pragma unroll
  for (int nt = 0; nt < 4; ++nt)
#pragma unroll
    for (int kk = 0; kk < 2; ++kk) {
      int row = nt * 16 + lr;
      int sl_ = lg + kk * 4;
      bf16x8 kf = *(const bf16x8*)(kbuf + row * 128 + ((sl_ ^ (row & 7)) << 4));
      sacc[nt] = __builtin_amdgcn_mfma_f32_16x16x32_bf16(kf, qf[kk], sacc[nt], 0, 0, 0);
    }
  __builtin_amdgcn_s_setprio(0);

  // ---- (diagonal) causal mask ----
  float pv[16];
#pragma unroll
  for (int nt = 0; nt < 4; ++nt)
#pragma unroll
    for (int r = 0; r < 4; ++r) {
      float v = sacc[nt][r];
      if (DIAG) {
        int jl = nt * 16 + lg * 4 + r;
        v = (jl <= il) ? v : -1e30f;
      }
      pv[nt * 4 + r] = v;
    }

  // ---- row max (relative to mrun): in-lane tree + 2 shuffles ----
  float m1 = pv[0];
#pragma unroll
  for (int i = 1; i < 16; ++i) m1 = fmaxf(m1, pv[i]);
  m1 = fmaxf(m1, __shfl_xor(m1, 16));
  m1 = fmaxf(m1, __shfl_xor(m1, 32));

  // ---- defer-max rescale (THR=8 in log2 units) ----
  if (__ballot(m1 > 8.f)) {
    float d = fmaxf(m1, 0.f);
    float fac = __builtin_amdgcn_exp2f(-d);
    mrun += d;
    lrun *= fac;
    int fi = __float_as_int(fac);
    float facr[4];
#pragma unroll
    for (int r = 0; r < 4; ++r)
      facr[r] = __int_as_float(__builtin_amdgcn_ds_bpermute((4 * lg + r) << 2, fi));
#pragma unroll
    for (int nt = 0; nt < 4; ++nt)
#pragma unroll
      for (int r = 0; r < 4; ++r) oacc[nt][r] *= facr[r];
#pragma unroll
    for (int i = 0; i < 16; ++i) pv[i] -= d;
  }

  // ---- exp2 + row sum ----
  float p[16];
  float rsum = 0.f;
#pragma unroll
  for (int i = 0; i < 16; ++i) {
    p[i] = __builtin_amdgcn_exp2f(pv[i]);
    rsum += p[i];
  }
  rsum += __shfl_xor(rsum, 16);
  rsum += __shfl_xor(rsum, 32);
  lrun += rsum;

  // ---- pack P -> per-wave swizzled LDS -> A-fragments ----
#pragma unroll
  for (int nt = 0; nt < 4; ++nt)
#pragma unroll
    for (int rp = 0; rp < 2; ++rp) {
      u32 pk;
      asm("v_cvt_pk_bf16_f32 %0, %1, %2" : "=v"(pk)
          : "v"(p[nt * 4 + 2 * rp]), "v"(p[nt * 4 + 2 * rp + 1]));
      *(u32*)(pbuf + ((lr * 128 + nt * 32 + lg * 8 + rp * 4) ^ ((lr & 7) << 4))) = pk;
    }
  asm volatile("s_waitcnt lgkmcnt(0)" ::: "memory");

  bf16x8 pf[2];
#pragma unroll
  for (int kk = 0; kk < 2; ++kk)
    pf[kk] = *(const bf16x8*)(pbuf + ((lr * 128 + (lg + 4 * kk) * 16) ^ ((lr & 7) << 4)));

  // ---- PV from LDS ----
  __builtin_amdgcn_s_setprio(1);
#pragma unroll
  for (int nt = 0; nt < 4; ++nt)
#pragma unroll
    for (int kk = 0; kk < 2; ++kk) {
      int row = nt * 16 + lr;
      int sl_ = lg + kk * 4;
      bf16x8 vf = *(const bf16x8*)(vbuf + row * 128 + ((sl_ ^ (row & 7)) << 4));
      oacc[nt] = __builtin_amdgcn_mfma_f32_16x16x32_bf16(pf[kk], vf, oacc[nt], 0, 0, 0);
    }
  __builtin_amdgcn_s_setprio(0);
}

// Flash attention: double-buffered LDS K/V, ONE barrier per tile, and the
// next-tile global prefetch issued AFTER the barrier so it overlaps compute.
// Heavy-first grid (qt = 31 - blockIdx.y).
__global__ __launch_bounds__(256, 3) void attn_kernel(const u16* __restrict__ qrot,
                                                      const u16* __restrict__ krot,
                                                      const u16* __restrict__ vt,
                                                      const float* __restrict__ log_xi,
                                                      const float* __restrict__ e_gate_logit,
                                                      u16* __restrict__ attnout) {
  int bh = blockIdx.x;
  int qt = 31 - blockIdx.y;
  int b = bh >> 4, h = bh & 15;
  int tid = threadIdx.x, w = tid >> 6, l = tid & 63, lg = l >> 4, lr = l & 15;
  int q0 = qt * 64;
  int il = w * 16 + lr;  // this lane's q-row, local to the 64-row tile

  const float L2E = 1.4426950408889634f;
  float eg = 1.0f / (1.0f + __expf(-e_gate_logit[h]));
  float cdec2 = eg * __expf(-log_xi[h]) * L2E;  // (e_g/xi) * log2e

  __shared__ __align__(16) unsigned char smem[40960];
  // [0:16384) kbuf[2], [16384:32768) vbuf[2], [32768:40960) pbuf per-wave
  unsigned char* pbuf = smem + 32768 + (w << 11);

  const size_t bhS = (size_t)bh * S_LEN;
  const u16* kb0 = krot + bhS * DH;
  const u16* vb0 = vt + (size_t)bh * DH * S_LEN;

  bf16x8 qf[2];
  {
    const u16* qp = qrot + (bhS + q0 + il) * DH + lg * 8;
    qf[0] = *(const bf16x8*)(qp);
    qf[1] = *(const bf16x8*)(qp + 32);
  }

  float cbv[16];
#pragma unroll
  for (int nt = 0; nt < 4; ++nt)
#pragma unroll
    for (int r = 0; r < 4; ++r)
      cbv[nt * 4 + r] = (float)(nt * 16 + lg * 4 + r) * cdec2;

  // staging geometry: 512 chunks of 16B per 8KB tile; this thread's 2 chunks
  int c0 = tid, c1 = 256 + tid;
  int row0 = c0 >> 3, sl0 = c0 & 7;
  int row1 = c1 >> 3, sl1 = c1 & 7;

  bf16x8 kr[2], vr[2];
  auto load_kv = [&](int t) {
    kr[0] = *(const bf16x8*)(kb0 + (size_t)(t * 64 + row0) * DH + sl0 * 8);
    kr[1] = *(const bf16x8*)(kb0 + (size_t)(t * 64 + row1) * DH + sl1 * 8);
    vr[0] = *(const bf16x8*)(vb0 + (size_t)row0 * S_LEN + t * 64 + sl0 * 8);
    vr[1] = *(const bf16x8*)(vb0 + (size_t)row1 * S_LEN + t * 64 + sl1 * 8);
  };
  auto stage = [&](int p) {
    unsigned char* kb = smem + p * 8192;
    unsigned char* vb = smem + 16384 + p * 8192;
    *(bf16x8*)(kb + row0 * 128 + ((sl0 ^ (row0 & 7)) << 4)) = kr[0];
    *(bf16x8*)(kb + row1 * 128 + ((sl1 ^ (row1 & 7)) << 4)) = kr[1];
    *(bf16x8*)(vb + row0 * 128 + ((sl0 ^ (row0 & 7)) << 4)) = vr[0];
    *(bf16x8*)(vb + row1 * 128 + ((sl1 ^ (row1 & 7)) << 4)) = vr[1];
  };

  f32x4 zero4 = {0.f, 0.f, 0.f, 0.f};
  f32x4 oacc[4];
#pragma unroll
  for (int nt = 0; nt < 4; ++nt) oacc[nt] = zero4;
  float mrun = 0.f, lrun = 0.f;

  load_kv(0);
  float step = 64.f * cdec2;
  float tb = 0.f;
  int p = 0;
  for (int t = 0; t < qt; ++t, tb += step, p ^= 1) {
    stage(p);           // dataflow-waits this tile's loads (issued last iter)
    __syncthreads();    // buf p visible; NOTHING outstanding -> free drain
    load_kv(t + 1);     // prefetch AFTER barrier: overlaps tile(p) compute
    attn_tile<false>(smem + p * 8192, smem + 16384 + p * 8192, tb - mrun, cbv,
                     qf, oacc, mrun, lrun, lg, lr, il, pbuf);
  }
  stage(p);
  __syncthreads();
  attn_tile<true>(smem + p * 8192, smem + 16384 + p * 8192, tb - mrun, cbv,
                  qf, oacc, mrun, lrun, lg, lr, il, pbuf);

  // ---- epilogue: redistribute l (lane p in 0..15 holds q-row p's sum) ----
  float lfin[4];
  int li = __float_as_int(lrun);
#pragma unroll
  for (int r = 0; r < 4; ++r)
    lfin[r] = __int_as_float(__builtin_amdgcn_ds_bpermute((4 * lg + r) << 2, li));
#pragma unroll
  for (int nt = 0; nt < 4; ++nt)
#pragma unroll
    for (int r = 0; r < 4; ++r) {
      int srow = q0 + w * 16 + lg * 4 + r;
      int col = h * DH + nt * 16 + lr;
      attnout[((size_t)b * S_LEN + srow) * DM + col] = f2bf(oacc[nt][r] / lfin[r]);
    }
}

// ---------------- launch ----------------
extern "C" void kernel_launch(void* const* d_in, const int* in_sizes, int n_in,
                              void* d_out, int out_size, void* d_ws, size_t ws_size,
                              hipStream_t stream) {
  const float* x    = (const float*)d_in[0];
  const float* Wqkv = (const float*)d_in[1];
  const float* Wo   = (const float*)d_in[2];
  const float* log_xi        = (const float*)d_in[3];
  const float* pi_gate_logit = (const float*)d_in[4];
  const float* e_gate_logit  = (const float*)d_in[5];

  u16* xb     = (u16*)d_ws;                 // 4096x1024
  u16* wqkvb  = xb + 4194304;               // 3072x1024
  u16* wob    = wqkvb + 3145728;            // 1024x1024
  u16* qrot   = wob + 1048576;              // 32x2048x64
  u16* krot   = qrot + 4194304;
  u16* vt     = krot + 4194304;             // 32x64x2048
  u16* attno  = vt + 4194304;               // 4096x1024

  conv3_kernel<<<4096, 256, 0, stream>>>(x, Wqkv, Wo, xb, wqkvb, wob);

  // GEMM1 with fused RoPE/relayout epilogue (writes qrot/krot/vt directly)
  gemm_bt<2><<<dim3(24, 32), 256, 0, stream>>>(xb, wqkvb, nullptr, 3072, 1024,
                                               pi_gate_logit, qrot, krot, vt);

  attn_kernel<<<dim3(32, 32), 256, 0, stream>>>(qrot, krot, vt, log_xi, e_gate_logit, attno);

  gemm_bt<1><<<dim3(8, 32), 256, 0, stream>>>(attno, wob, d_out, 1024, 1024,
                                              nullptr, nullptr, nullptr, nullptr);
}